// Round 1
// baseline (551.806 us; speedup 1.0000x reference)
//
#include <hip/hip_runtime.h>

typedef unsigned short u16;
typedef __bf16 bf16x8 __attribute__((ext_vector_type(8)));
typedef float f32x4 __attribute__((ext_vector_type(4)));
typedef u16 u16x8 __attribute__((ext_vector_type(8)));

#define M_DIM 8192
#define N_DIM 4096
#define K_DIM 4096

// Round-to-nearest-even fp32 -> bf16 (truncation's bias would cost ~0.3 absmax
// over K=4096 sums; RNE keeps error ~0.01 std).
__device__ __forceinline__ u16 f2bf(float f) {
  unsigned int u = __float_as_uint(f);
  u += 0x7fffu + ((u >> 16) & 1u);
  return (u16)(u >> 16);
}

// ---------------- pre-pass 1: dequantize packed nibbles -> W bf16 [N][K] ----
__global__ __launch_bounds__(256) void dequant_kernel(
    const int* __restrict__ packed, const float* __restrict__ mn,
    const float* __restrict__ scale, u16* __restrict__ W) {
  int idx = blockIdx.x * 256 + threadIdx.x;  // one thread per packed int32
  int j = idx & 31;                          // position within half-group
  int g = (idx >> 5) & 63;                   // group
  int n = idx >> 11;                         // output row
  int p = packed[idx];
  float inv = 1.0f / scale[(n << 6) + g];
  float m = mn[(n << 6) + g];
  float hi = (float)((p >> 4) & 0xF) * inv + m;  // first half of group
  float lo = (float)(p & 0xF) * inv + m;         // second half of group
  int base = (n << 12) + (g << 6) + j;
  W[base] = f2bf(hi);
  W[base + 32] = f2bf(lo);
}

// ---------------- pre-pass 2: X fp32 -> bf16, 8 elems/thread ---------------
__global__ __launch_bounds__(256) void cvt_kernel(const float4* __restrict__ x,
                                                  u16x8* __restrict__ xb) {
  int i = blockIdx.x * 256 + threadIdx.x;
  float4 a = x[2 * i];
  float4 b = x[2 * i + 1];
  u16x8 o;
  o[0] = f2bf(a.x); o[1] = f2bf(a.y); o[2] = f2bf(a.z); o[3] = f2bf(a.w);
  o[4] = f2bf(b.x); o[5] = f2bf(b.y); o[6] = f2bf(b.z); o[7] = f2bf(b.w);
  xb[i] = o;
}

// ---------------- main GEMM: C[M][N] = A[M][K] * B[N][K]^T + bias ----------
// m97 structure: 128x128 tile, BK=32, global_load_lds width=16, 2-barrier.
__device__ __forceinline__ void gload_lds16(const u16* g, u16* l) {
  __builtin_amdgcn_global_load_lds(
      (const __attribute__((address_space(1))) void*)g,
      (__attribute__((address_space(3))) void*)l, 16, 0, 0);
}

__global__ __launch_bounds__(256) void gemm_kernel(
    const u16* __restrict__ A,   // [8192][4096] bf16
    const u16* __restrict__ B,   // [4096][4096] bf16 = W[n][k]
    const float* __restrict__ bias,
    float* __restrict__ C) {
  // Unpadded [128][32] row-major (64 B rows): global_load_lds scatter is
  // wave-uniform base + lane*16, padding would break it.
  __shared__ alignas(16) u16 As[128 * 32];
  __shared__ alignas(16) u16 Bs[128 * 32];

  const int tid = threadIdx.x;
  const int wave = tid >> 6;
  const int lane = tid & 63;
  const int lr = lane & 15;   // fragment row (m for A, n for B)
  const int lq = lane >> 4;   // quad: k-offset = lq*8

  const int bn = blockIdx.x & 31;
  const int bm = blockIdx.x >> 5;
  const int m0 = bm << 7;
  const int n0 = bn << 7;

  // 4 waves in 2x2 over the 128x128 tile; each wave owns 64x64 = 4x4 MFMAs.
  const int wm = (wave & 1) << 6;
  const int wn = (wave >> 1) << 6;

  // Staging: tile = 8192 B = 2 passes x 4 waves x 64 lanes x 16 B.
  // pass-0 byte offset = wave*1024 + lane*16; pass-1 adds 4096 (row +64).
  const int off0 = (wave << 10) + (lane << 4);
  const int srow = off0 >> 6;          // 0..63
  const int scol = (off0 & 63) >> 1;   // u16 index 0..31 within BK

  const u16* gA = A + (size_t)(m0 + srow) * K_DIM + scol;
  const u16* gB = B + (size_t)(n0 + srow) * K_DIM + scol;
  u16* ldsA0 = As + ((wave << 10) >> 1);         // wave-uniform LDS base
  u16* ldsB0 = Bs + ((wave << 10) >> 1);

  f32x4 acc[4][4] = {};

  for (int k0 = 0; k0 < K_DIM; k0 += 32) {
    gload_lds16(gA + k0, ldsA0);
    gload_lds16(gA + (size_t)64 * K_DIM + k0, ldsA0 + 2048);
    gload_lds16(gB + k0, ldsB0);
    gload_lds16(gB + (size_t)64 * K_DIM + k0, ldsB0 + 2048);
    __syncthreads();  // compiler emits vmcnt(0) drain before s_barrier

    bf16x8 af[4], bfr[4];
#pragma unroll
    for (int i = 0; i < 4; i++)
      af[i] = *(const bf16x8*)(As + (wm + i * 16 + lr) * 32 + lq * 8);
#pragma unroll
    for (int j = 0; j < 4; j++)
      bfr[j] = *(const bf16x8*)(Bs + (wn + j * 16 + lr) * 32 + lq * 8);
#pragma unroll
    for (int i = 0; i < 4; i++)
#pragma unroll
      for (int j = 0; j < 4; j++)
        acc[i][j] = __builtin_amdgcn_mfma_f32_16x16x32_bf16(af[i], bfr[j],
                                                            acc[i][j], 0, 0, 0);
    __syncthreads();
  }

  // Epilogue: C/D layout col = lane&15, row = (lane>>4)*4 + t  (m89-verified).
#pragma unroll
  for (int j = 0; j < 4; j++) {
    int n = n0 + wn + j * 16 + lr;
    float bv = bias[n];
#pragma unroll
    for (int i = 0; i < 4; i++) {
      int mb = m0 + wm + i * 16 + lq * 4;
#pragma unroll
      for (int t = 0; t < 4; t++)
        C[(size_t)(mb + t) * N_DIM + n] = acc[i][j][t] + bv;
    }
  }
}

// ---------------- fallback (only if ws too small): naive tiled fp32 --------
__global__ __launch_bounds__(256) void fallback_gemm(
    const float* __restrict__ x, const int* __restrict__ packed,
    const float* __restrict__ mn, const float* __restrict__ scale,
    const float* __restrict__ bias, float* __restrict__ out) {
  __shared__ float As[16][17];
  __shared__ float Bs[16][17];
  int tx = threadIdx.x & 15, ty = threadIdx.x >> 4;
  int m = blockIdx.y * 16 + ty;
  int n = blockIdx.x * 16 + tx;
  float acc = 0.f;
  for (int k0 = 0; k0 < K_DIM; k0 += 16) {
    As[ty][tx] = x[(size_t)m * K_DIM + k0 + tx];
    int nn = blockIdx.x * 16 + ty;
    int k = k0 + tx;
    int g = k >> 6, pos = k & 63;
    int p = packed[nn * 2048 + g * 32 + (pos & 31)];
    int v = (pos < 32) ? ((p >> 4) & 0xF) : (p & 0xF);
    Bs[ty][tx] = (float)v / scale[nn * 64 + g] + mn[nn * 64 + g];
    __syncthreads();
#pragma unroll
    for (int kk = 0; kk < 16; kk++) acc += As[ty][kk] * Bs[tx][kk];
    __syncthreads();
  }
  out[(size_t)m * N_DIM + n] = acc + bias[n];
}

extern "C" void kernel_launch(void* const* d_in, const int* in_sizes, int n_in,
                              void* d_out, int out_size, void* d_ws, size_t ws_size,
                              hipStream_t stream) {
  const float* x = (const float*)d_in[0];      // [4,2048,4096] fp32
  const int* packed = (const int*)d_in[1];     // [4096,64,32] int32
  const float* mn = (const float*)d_in[2];     // [4096,64,1]
  const float* scale = (const float*)d_in[3];  // [4096,64,1]
  const float* bias = (const float*)d_in[4];   // [4096]
  float* out = (float*)d_out;                  // [8192,4096]

  const size_t needW = (size_t)N_DIM * K_DIM * 2;  // 32 MB
  const size_t needX = (size_t)M_DIM * K_DIM * 2;  // 64 MB

  if (ws_size >= needW + needX) {
    u16* W = (u16*)d_ws;
    u16* Xb = (u16*)((char*)d_ws + needW);
    dequant_kernel<<<(N_DIM * 64 * 32) / 256, 256, 0, stream>>>(packed, mn,
                                                                scale, W);
    cvt_kernel<<<(size_t)M_DIM * K_DIM / (256 * 8), 256, 0, stream>>>(
        (const float4*)x, (u16x8*)Xb);
    gemm_kernel<<<(M_DIM / 128) * (N_DIM / 128), 256, 0, stream>>>(Xb, W, bias,
                                                                   out);
  } else {
    dim3 grid(N_DIM / 16, M_DIM / 16);
    fallback_gemm<<<grid, 256, 0, stream>>>(x, packed, mn, scale, bias, out);
  }
}

// Round 2
// 529.209 us; speedup vs baseline: 1.0427x; 1.0427x over previous
//
#include <hip/hip_runtime.h>

typedef unsigned short u16;
typedef __bf16 bf16x8 __attribute__((ext_vector_type(8)));
typedef float f32x4 __attribute__((ext_vector_type(4)));

#define M_DIM 8192
#define N_DIM 4096
#define K_DIM 4096

// Round-to-nearest-even fp32 -> bf16 (truncation's systematic bias over
// K=4096 sums would eat most of the 0.4775 absmax budget; RNE keeps it ~0.1).
__device__ __forceinline__ u16 f2bf(float f) {
  unsigned int u = __float_as_uint(f);
  u += 0x7fffu + ((u >> 16) & 1u);
  return (u16)(u >> 16);
}

// ---- fused pre-pass: blocks [0,32768) dequant W, [32768,65536) convert X ---
#define DQ_BLOCKS 32768  // 4096*64*32 int32 words / 256 threads
__global__ __launch_bounds__(256) void prep_kernel(
    const int* __restrict__ packed, const float* __restrict__ mn,
    const float* __restrict__ scale, u16* __restrict__ W,
    const float4* __restrict__ x, ushort4* __restrict__ xb) {
  int b = blockIdx.x;
  if (b < DQ_BLOCKS) {
    int idx = b * 256 + threadIdx.x;  // one thread per packed int32
    int j = idx & 31;                 // position within half-group
    int g = (idx >> 5) & 63;          // group
    int n = idx >> 11;                // output row
    int p = packed[idx];
    float inv = 1.0f / scale[(n << 6) + g];
    float m = mn[(n << 6) + g];
    float hi = (float)((p >> 4) & 0xF) * inv + m;  // first half of group
    float lo = (float)(p & 0xF) * inv + m;         // second half of group
    int base = (n << 12) + (g << 6) + j;
    W[base] = f2bf(hi);
    W[base + 32] = f2bf(lo);
  } else {
    // X fp32->bf16: 1 float4 load, 1 ushort4 store, fully coalesced.
    int i = (b - DQ_BLOCKS) * 256 + threadIdx.x;
    float4 a = x[i];
    ushort4 o;
    o.x = f2bf(a.x); o.y = f2bf(a.y); o.z = f2bf(a.z); o.w = f2bf(a.w);
    xb[i] = o;
  }
}

// ---------------- main GEMM: C[M][N] = A[M][K] * B[N][K]^T + bias ----------
// m97 structure + BK=64 staged as two 32-wide subtiles: same 64B-row LDS
// geometry (no new bank conflicts), half the barrier drains vs BK=32.
__device__ __forceinline__ void gload_lds16(const u16* g, u16* l) {
  __builtin_amdgcn_global_load_lds(
      (const __attribute__((address_space(1))) void*)g,
      (__attribute__((address_space(3))) void*)l, 16, 0, 0);
}

__global__ __launch_bounds__(256) void gemm_kernel(
    const u16* __restrict__ A,   // [8192][4096] bf16
    const u16* __restrict__ B,   // [4096][4096] bf16 = W[n][k]
    const float* __restrict__ bias,
    float* __restrict__ C) {
  // Two unpadded [128][32] subtiles per matrix (global_load_lds scatter is
  // wave-uniform base + lane*16 -- padding would break the landing pattern).
  __shared__ alignas(16) u16 As[2 * 128 * 32];  // 16 KB
  __shared__ alignas(16) u16 Bs[2 * 128 * 32];  // 16 KB

  const int tid = threadIdx.x;
  const int wave = tid >> 6;
  const int lane = tid & 63;
  const int lr = lane & 15;   // fragment row (m for A, n for B)
  const int lq = lane >> 4;   // quad: k-offset = lq*8

  const int bn = blockIdx.x & 31;
  const int bm = blockIdx.x >> 5;
  const int m0 = bm << 7;
  const int n0 = bn << 7;

  // 4 waves in 2x2 over the 128x128 tile; each wave owns 64x64 = 4x4 MFMAs.
  const int wm = (wave & 1) << 6;
  const int wn = (wave >> 1) << 6;

  // Staging within one 8KB subtile: 2 passes x 4 waves x 64 lanes x 16B.
  const int off0 = (wave << 10) + (lane << 4);  // byte offset, pass 0
  const int srow = off0 >> 6;                   // 0..63
  const int scol = (off0 & 63) >> 1;            // u16 col 0..31

  const u16* gA = A + (size_t)(m0 + srow) * K_DIM + scol;
  const u16* gB = B + (size_t)(n0 + srow) * K_DIM + scol;
  u16* ldsA0 = As + (wave << 9);  // wave-uniform LDS base (u16 units)
  u16* ldsB0 = Bs + (wave << 9);

  f32x4 acc[4][4] = {};

  for (int k0 = 0; k0 < K_DIM; k0 += 64) {
    // subtile 0: k in [k0, k0+32)
    gload_lds16(gA + k0, ldsA0);
    gload_lds16(gA + (size_t)64 * K_DIM + k0, ldsA0 + 2048);
    gload_lds16(gB + k0, ldsB0);
    gload_lds16(gB + (size_t)64 * K_DIM + k0, ldsB0 + 2048);
    // subtile 1: k in [k0+32, k0+64)
    gload_lds16(gA + k0 + 32, ldsA0 + 4096);
    gload_lds16(gA + (size_t)64 * K_DIM + k0 + 32, ldsA0 + 6144);
    gload_lds16(gB + k0 + 32, ldsB0 + 4096);
    gload_lds16(gB + (size_t)64 * K_DIM + k0 + 32, ldsB0 + 6144);
    __syncthreads();  // one vmcnt(0) drain per 64-K (was per 32-K)

#pragma unroll
    for (int s = 0; s < 2; s++) {
      const u16* as = As + s * 4096;
      const u16* bs = Bs + s * 4096;
      bf16x8 af[4], bfr[4];
#pragma unroll
      for (int i = 0; i < 4; i++)
        af[i] = *(const bf16x8*)(as + (wm + i * 16 + lr) * 32 + lq * 8);
#pragma unroll
      for (int j = 0; j < 4; j++)
        bfr[j] = *(const bf16x8*)(bs + (wn + j * 16 + lr) * 32 + lq * 8);
#pragma unroll
      for (int i = 0; i < 4; i++)
#pragma unroll
        for (int j = 0; j < 4; j++)
          acc[i][j] = __builtin_amdgcn_mfma_f32_16x16x32_bf16(
              af[i], bfr[j], acc[i][j], 0, 0, 0);
    }
    __syncthreads();
  }

  // Epilogue: C/D layout col = lane&15, row = (lane>>4)*4 + t  (m89-verified).
#pragma unroll
  for (int j = 0; j < 4; j++) {
    int n = n0 + wn + j * 16 + lr;
    float bv = bias[n];
#pragma unroll
    for (int i = 0; i < 4; i++) {
      int mb = m0 + wm + i * 16 + lq * 4;
#pragma unroll
      for (int t = 0; t < 4; t++)
        C[(size_t)(mb + t) * N_DIM + n] = acc[i][j][t] + bv;
    }
  }
}

// ---------------- fallback (only if ws too small): naive tiled fp32 --------
__global__ __launch_bounds__(256) void fallback_gemm(
    const float* __restrict__ x, const int* __restrict__ packed,
    const float* __restrict__ mn, const float* __restrict__ scale,
    const float* __restrict__ bias, float* __restrict__ out) {
  __shared__ float As[16][17];
  __shared__ float Bs[16][17];
  int tx = threadIdx.x & 15, ty = threadIdx.x >> 4;
  int m = blockIdx.y * 16 + ty;
  int n = blockIdx.x * 16 + tx;
  float acc = 0.f;
  for (int k0 = 0; k0 < K_DIM; k0 += 16) {
    As[ty][tx] = x[(size_t)m * K_DIM + k0 + tx];
    int nn = blockIdx.x * 16 + ty;
    int k = k0 + tx;
    int g = k >> 6, pos = k & 63;
    int p = packed[nn * 2048 + g * 32 + (pos & 31)];
    int v = (pos < 32) ? ((p >> 4) & 0xF) : (p & 0xF);
    Bs[ty][tx] = (float)v / scale[nn * 64 + g] + mn[nn * 64 + g];
    __syncthreads();
#pragma unroll
    for (int kk = 0; kk < 16; kk++) acc += As[ty][kk] * Bs[tx][kk];
    __syncthreads();
  }
  out[(size_t)m * N_DIM + n] = acc + bias[n];
}

extern "C" void kernel_launch(void* const* d_in, const int* in_sizes, int n_in,
                              void* d_out, int out_size, void* d_ws, size_t ws_size,
                              hipStream_t stream) {
  const float* x = (const float*)d_in[0];      // [4,2048,4096] fp32
  const int* packed = (const int*)d_in[1];     // [4096,64,32] int32
  const float* mn = (const float*)d_in[2];     // [4096,64,1]
  const float* scale = (const float*)d_in[3];  // [4096,64,1]
  const float* bias = (const float*)d_in[4];   // [4096]
  float* out = (float*)d_out;                  // [8192,4096]

  const size_t needW = (size_t)N_DIM * K_DIM * 2;  // 32 MB
  const size_t needX = (size_t)M_DIM * K_DIM * 2;  // 64 MB

  if (ws_size >= needW + needX) {
    u16* W = (u16*)d_ws;
    u16* Xb = (u16*)((char*)d_ws + needW);
    const int cvt_blocks = (int)((size_t)M_DIM * K_DIM / 4 / 256);  // 32768
    prep_kernel<<<DQ_BLOCKS + cvt_blocks, 256, 0, stream>>>(
        packed, mn, scale, W, (const float4*)x, (ushort4*)Xb);
    gemm_kernel<<<(M_DIM / 128) * (N_DIM / 128), 256, 0, stream>>>(Xb, W, bias,
                                                                   out);
  } else {
    dim3 grid(N_DIM / 16, M_DIM / 16);
    fallback_gemm<<<grid, 256, 0, stream>>>(x, packed, mn, scale, bias, out);
  }
}

// Round 4
// 513.000 us; speedup vs baseline: 1.0756x; 1.0316x over previous
//
#include <hip/hip_runtime.h>

typedef unsigned short u16;
typedef unsigned int u32;
typedef _Float16 f16;
typedef f16 f16x2 __attribute__((ext_vector_type(2)));
typedef f16 f16x8 __attribute__((ext_vector_type(8)));
typedef __fp16 h16x2 __attribute__((ext_vector_type(2)));  // pkrtz return type
typedef float f32x4 __attribute__((ext_vector_type(4)));

#define M_DIM 8192
#define N_DIM 4096
#define K_DIM 4096

// ---------------------------------------------------------------------------
// Fused pre-pass.
//  range 0: X fp32 -> fp16 (8 elems/thread, pkrtz)
//  range 1: repack 4-bit weights into splice-friendly nibble order:
//           dword w of row n covers k=[8w,8w+8); nibble positions
//           k0->bits[3:0], k2->[7:4], k4->[11:8], k6->[15:12],
//           k1->[19:16], k3->[23:20], k5->[27:24], k7->[31:28]
//           so that (d<<6)&0x03C003C0 gives the fp16 mantissa bits of the
//           (k0,k1) pair, (d<<2) the (k2,k3) pair, (d>>2) (k4,k5), (d>>6) (k6,k7).
//  range 2: invmn[g][n] = { dup16(f16(1/scale)), dup16(f16(mn - 16*f16(1/scale))) }
//           (the splice yields fp16(16+v) exactly; pk_fma removes the +16)
// ---------------------------------------------------------------------------
#define XCVT_BLOCKS 16384  // M*K/8/256
#define W4_BLOCKS 8192     // N*(K/8)/256
#define IM_BLOCKS 1024     // 64*N/256

__global__ __launch_bounds__(256) void prep_kernel(
    const float4* __restrict__ x, uint4* __restrict__ xh,
    const int* __restrict__ packed, u32* __restrict__ w4,
    const float* __restrict__ mn, const float* __restrict__ scale,
    uint2* __restrict__ invmn) {
  int b = blockIdx.x;
  if (b < XCVT_BLOCKS) {
    int i = b * 256 + threadIdx.x;
    float4 a0 = x[2 * i], a1 = x[2 * i + 1];
    h16x2 h0 = __builtin_amdgcn_cvt_pkrtz(a0.x, a0.y);
    h16x2 h1 = __builtin_amdgcn_cvt_pkrtz(a0.z, a0.w);
    h16x2 h2 = __builtin_amdgcn_cvt_pkrtz(a1.x, a1.y);
    h16x2 h3 = __builtin_amdgcn_cvt_pkrtz(a1.z, a1.w);
    uint4 o;
    o.x = __builtin_bit_cast(u32, h0);
    o.y = __builtin_bit_cast(u32, h1);
    o.z = __builtin_bit_cast(u32, h2);
    o.w = __builtin_bit_cast(u32, h3);
    xh[i] = o;
  } else if (b < XCVT_BLOCKS + W4_BLOCKS) {
    int idx = (b - XCVT_BLOCKS) * 256 + threadIdx.x;  // n*512 + w
    int n = idx >> 9, w = idx & 511;
    int g = w >> 3;
    int jb = (w & 7) << 3;                      // 0..56; <32 = hi nibbles
    int sh = (jb < 32) ? 4 : 0;
    const int* p = packed + n * 2048 + g * 32 + (jb & 31);
    u32 out = 0;
#pragma unroll
    for (int t = 0; t < 8; t++) {
      u32 nib = ((u32)p[t] >> sh) & 0xFu;
      int pos = ((t & 1) ? 16 : 0) + ((t >> 1) << 2);
      out |= nib << pos;
    }
    w4[idx] = out;
  } else {
    int idx = (b - XCVT_BLOCKS - W4_BLOCKS) * 256 + threadIdx.x;  // g*4096+n
    int n = idx & 4095, g = idx >> 12;
    float sc = scale[n * 64 + g];
    float m = mn[n * 64 + g];
    f16 invh = (f16)(1.0f / sc);
    f16 mnh = (f16)(m - 16.0f * (float)invh);
    u32 ib = (u32)__builtin_bit_cast(u16, invh);
    u32 mb = (u32)__builtin_bit_cast(u16, mnh);
    uint2 o;
    o.x = ib | (ib << 16);
    o.y = mb | (mb << 16);
    invmn[idx] = o;
  }
}

// ---------------------------------------------------------------------------
// GEMM: C[M][N] = Xh[M][K](fp16) * dequant(B4)[N][K]^T + bias
// Block 256x128 tile, 4 waves in 2x2, wave-tile 128x64 (8x4 MFMAs of
// 16x16x32 f16 per K32). A staged fp16 via global_load_lds; B staged as raw
// nibbles (ds_read_b32 per frag, conflict-free), spliced to fp16 in-register.
// LDS bytes/FLOP = 0.0176 < machine 0.0189 -> MFMA-bound structure.
// ---------------------------------------------------------------------------
__device__ __forceinline__ void gload_lds16(const void* g, void* l) {
  __builtin_amdgcn_global_load_lds(
      (const __attribute__((address_space(1))) void*)g,
      (__attribute__((address_space(3))) void*)l, 16, 0, 0);
}

__global__ __launch_bounds__(256, 2) void gemm4_kernel(
    const u16* __restrict__ A,     // fp16 [8192][4096]
    const u32* __restrict__ B4,    // [4096][512] splice-ordered nibble dwords
    const uint2* __restrict__ IM,  // [64][4096] {inv2, mn2}
    const float* __restrict__ bias, float* __restrict__ C) {
  __shared__ alignas(16) u16 As[2][256 * 32];  // [k32-subtile][row][32] 32 KB
  __shared__ alignas(16) u32 Bs[2][128 * 4];   // [k32-half][row][4 dw]  4 KB

  const int tid = threadIdx.x;
  const int wave = tid >> 6, lane = tid & 63;
  const int lr = lane & 15, lq = lane >> 4;
  const int bn = blockIdx.x & 31, bm = blockIdx.x >> 5;
  const int m0 = bm << 8, n0 = bn << 7;
  const int wm = (wave & 1) << 7, wn = (wave >> 1) << 6;

  // A staging: wave covers rows 64*wave..+63 over 4 passes (c), 2 subtiles (s)
  const u16* pA =
      A + (size_t)(m0 + (wave << 6) + (lane >> 2)) * K_DIM + ((lane & 3) << 3);
  char* dstA = (char*)(&As[0][0]) + wave * 4096 + lane * 16;
  // B staging: 1 pass/wave: h = wave>>1, row = 64*(wave&1)+lane (dword units)
  const u32* pB = B4 + (size_t)(n0 + ((wave & 1) << 6) + lane) * 512 +
                  ((wave >> 1) << 2);
  char* dstB = (char*)(&Bs[0][0]) + wave * 1024 + lane * 16;
  const uint2* pI = IM + n0 + wn + lr;

  f32x4 acc[8][4] = {};

  for (int kk = 0; kk < 64; ++kk) {  // k0 = kk*64; group g == kk
    uint2 im[4];
    const uint2* pIt = pI + kk * 4096;
#pragma unroll
    for (int j = 0; j < 4; j++) im[j] = pIt[j * 16];

#pragma unroll
    for (int s = 0; s < 2; s++)
#pragma unroll
      for (int c = 0; c < 4; c++)
        gload_lds16(pA + kk * 64 + s * 32 + (size_t)c * 16 * K_DIM,
                    dstA + s * 16384 + c * 1024);
    gload_lds16(pB + kk * 8, dstB);
    __syncthreads();  // vmcnt(0) drain (also covers im[])

#pragma unroll
    for (int s = 0; s < 2; s++) {
      f16x8 af[8];
#pragma unroll
      for (int i = 0; i < 8; i++)
        af[i] = *(const f16x8*)((const char*)(&As[0][0]) + s * 16384 +
                                (wm + i * 16 + lr) * 64 + lq * 16);
      u32 braw[4];
#pragma unroll
      for (int j = 0; j < 4; j++) braw[j] = Bs[s][(wn + j * 16 + lr) * 4 + lq];

      f16x8 bf[4];
#pragma unroll
      for (int j = 0; j < 4; j++) {
        u32 d = braw[j];
        u32 q0 = ((d << 6) & 0x03C003C0u) | 0x4C004C00u;  // fp16(16+v) pairs
        u32 q1 = ((d << 2) & 0x03C003C0u) | 0x4C004C00u;
        u32 q2 = ((d >> 2) & 0x03C003C0u) | 0x4C004C00u;
        u32 q3 = ((d >> 6) & 0x03C003C0u) | 0x4C004C00u;
        f16x2 inv2 = __builtin_bit_cast(f16x2, im[j].x);
        f16x2 mn2 = __builtin_bit_cast(f16x2, im[j].y);
        f16x2 w0 = __builtin_elementwise_fma(__builtin_bit_cast(f16x2, q0), inv2, mn2);
        f16x2 w1 = __builtin_elementwise_fma(__builtin_bit_cast(f16x2, q1), inv2, mn2);
        f16x2 w2 = __builtin_elementwise_fma(__builtin_bit_cast(f16x2, q2), inv2, mn2);
        f16x2 w3 = __builtin_elementwise_fma(__builtin_bit_cast(f16x2, q3), inv2, mn2);
        union {
          f16x8 v;
          u32 d[4];
        } u;
        u.d[0] = __builtin_bit_cast(u32, w0);
        u.d[1] = __builtin_bit_cast(u32, w1);
        u.d[2] = __builtin_bit_cast(u32, w2);
        u.d[3] = __builtin_bit_cast(u32, w3);
        bf[j] = u.v;
      }
#pragma unroll
      for (int i = 0; i < 8; i++)
#pragma unroll
        for (int j = 0; j < 4; j++)
          acc[i][j] = __builtin_amdgcn_mfma_f32_16x16x32_f16(af[i], bf[j],
                                                             acc[i][j], 0, 0, 0);
    }
    __syncthreads();
  }

  // Epilogue: C/D layout col=lane&15, row=(lane>>4)*4+t (same as verified r1/r2)
#pragma unroll
  for (int j = 0; j < 4; j++) {
    int n = n0 + wn + j * 16 + lr;
    float bv = bias[n];
#pragma unroll
    for (int i = 0; i < 8; i++) {
      int mb = m0 + wm + i * 16 + (lq << 2);
#pragma unroll
      for (int t = 0; t < 4; t++)
        C[(size_t)(mb + t) * N_DIM + n] = acc[i][j][t] + bv;
    }
  }
}

// ---------------- fallback (only if ws too small): naive tiled fp32 --------
__global__ __launch_bounds__(256) void fallback_gemm(
    const float* __restrict__ x, const int* __restrict__ packed,
    const float* __restrict__ mn, const float* __restrict__ scale,
    const float* __restrict__ bias, float* __restrict__ out) {
  __shared__ float As[16][17];
  __shared__ float Bs[16][17];
  int tx = threadIdx.x & 15, ty = threadIdx.x >> 4;
  int m = blockIdx.y * 16 + ty;
  int n = blockIdx.x * 16 + tx;
  float acc = 0.f;
  for (int k0 = 0; k0 < K_DIM; k0 += 16) {
    As[ty][tx] = x[(size_t)m * K_DIM + k0 + tx];
    int nn = blockIdx.x * 16 + ty;
    int k = k0 + tx;
    int g = k >> 6, pos = k & 63;
    int p = packed[nn * 2048 + g * 32 + (pos & 31)];
    int v = (pos < 32) ? ((p >> 4) & 0xF) : (p & 0xF);
    Bs[ty][tx] = (float)v / scale[nn * 64 + g] + mn[nn * 64 + g];
    __syncthreads();
#pragma unroll
    for (int kk = 0; kk < 16; kk++) acc += As[ty][kk] * Bs[tx][kk];
    __syncthreads();
  }
  out[(size_t)m * N_DIM + n] = acc + bias[n];
}

extern "C" void kernel_launch(void* const* d_in, const int* in_sizes, int n_in,
                              void* d_out, int out_size, void* d_ws,
                              size_t ws_size, hipStream_t stream) {
  const float* x = (const float*)d_in[0];      // [4,2048,4096] fp32
  const int* packed = (const int*)d_in[1];     // [4096,64,32] int32
  const float* mn = (const float*)d_in[2];     // [4096,64,1]
  const float* scale = (const float*)d_in[3];  // [4096,64,1]
  const float* bias = (const float*)d_in[4];   // [4096]
  float* out = (float*)d_out;                  // [8192,4096]

  const size_t offW4 = (size_t)M_DIM * K_DIM * 2;          // Xh: 64 MB
  const size_t offIM = offW4 + (size_t)N_DIM * K_DIM / 2;  // W4: 8 MB
  const size_t need = offIM + (size_t)64 * N_DIM * 8;      // IM: 2 MB

  if (ws_size >= need) {
    u16* Xh = (u16*)d_ws;
    u32* W4 = (u32*)((char*)d_ws + offW4);
    uint2* IMp = (uint2*)((char*)d_ws + offIM);
    prep_kernel<<<XCVT_BLOCKS + W4_BLOCKS + IM_BLOCKS, 256, 0, stream>>>(
        (const float4*)x, (uint4*)Xh, packed, W4, mn, scale, IMp);
    gemm4_kernel<<<(M_DIM / 256) * (N_DIM / 128), 256, 0, stream>>>(
        Xh, W4, IMp, bias, out);
  } else {
    dim3 grid(N_DIM / 16, M_DIM / 16);
    fallback_gemm<<<grid, 256, 0, stream>>>(x, packed, mn, scale, bias, out);
  }
}